// Round 1
// baseline (544.717 us; speedup 1.0000x reference)
//
#include <hip/hip_runtime.h>
#include <math.h>

#define B_N 256
#define F_N 512
#define S_N 100000
#define Q_N 1024
#define EPSF 1e-12f
#define NCHUNK ((S_N + 63) / 64)   // 1563

__device__ __forceinline__ float warpReduceSum(float v) {
  #pragma unroll
  for (int o = 32; o > 0; o >>= 1) v += __shfl_down(v, o);
  return v;
}

// 256-thread block reduce, result broadcast to all threads
__device__ __forceinline__ float blockReduceSum256(float v, float* buf) {
  v = warpReduceSum(v);
  int lane = threadIdx.x & 63, w = threadIdx.x >> 6;
  __syncthreads();
  if (lane == 0) buf[w] = v;
  __syncthreads();
  return buf[0] + buf[1] + buf[2] + buf[3];
}

// -------- K0: L_norm, org, aug (one block per b) --------
__global__ __launch_bounds__(256) void k_prep(const float* __restrict__ V,
    const float* __restrict__ L, float* __restrict__ org, float* __restrict__ aug) {
  __shared__ float buf[4];
  int b = blockIdx.x, t = threadIdx.x;
  const float2 lv = *(const float2*)&L[b * F_N + t * 2];
  float ss = blockReduceSum256(lv.x * lv.x + lv.y * lv.y, buf);
  float invL = 1.0f / fmaxf(sqrtf(ss), EPSF);
  float lnx = lv.x * invL, lny = lv.y * invL;
  #pragma unroll
  for (int a = 0; a < 3; ++a) {
    const float2 vv = *(const float2*)&V[(a * B_N + b) * F_N + t * 2];
    float yx = vv.x * lnx, yy = vv.y * lny;
    float s2 = blockReduceSum256(yx * yx + yy * yy, buf);
    float inv = 1.0f / fmaxf(sqrtf(s2), EPSF);
    float* dst = (a == 0) ? &org[b * F_N + t * 2]
                          : &aug[((a - 1) * B_N + b) * F_N + t * 2];
    dst[0] = yx * inv;
    dst[1] = yy * inv;
  }
}

// -------- K1: sims = support @ org^T, column argmax via atomic u64 keys --------
// block: 64 support rows x all 256 b. threads 256 = (ts 16) x (tb 16),
// thread tile = 4 s x 16 b.
__global__ __launch_bounds__(256) void k_sims(const float* __restrict__ support,
    const float* __restrict__ org, unsigned long long* __restrict__ keys) {
  __shared__ __align__(16) unsigned char smem[32768];
  float (*As)[64]  = (float (*)[64])smem;            // 4 KB  [k][s]
  float (*Bs)[256] = (float (*)[256])(smem + 4096);  // 16 KB [k][b]
  float (*cv)[256] = (float (*)[256])smem;           // overlay after K loop
  int   (*ci)[256] = (int (*)[256])(smem + 16384);

  int t = threadIdx.x;
  int ts = t & 15, tb = t >> 4;
  int s0 = blockIdx.x * 64;

  float acc[4][16];
  #pragma unroll
  for (int i = 0; i < 4; ++i)
    #pragma unroll
    for (int j = 0; j < 16; ++j) acc[i][j] = 0.f;

  int ar = t >> 2, ak = t & 3;
  const bool avalid = (s0 + ar) < S_N;

  for (int k0 = 0; k0 < F_N; k0 += 16) {
    float4 av = make_float4(0.f, 0.f, 0.f, 0.f);
    if (avalid)
      av = *(const float4*)&support[(long long)(s0 + ar) * F_N + k0 + ak * 4];
    As[ak * 4 + 0][ar] = av.x; As[ak * 4 + 1][ar] = av.y;
    As[ak * 4 + 2][ar] = av.z; As[ak * 4 + 3][ar] = av.w;
    #pragma unroll
    for (int i = 0; i < 4; ++i) {
      int q = t + 256 * i; int bb = q >> 2, kq = q & 3;
      float4 bv = *(const float4*)&org[bb * F_N + k0 + kq * 4];
      Bs[kq * 4 + 0][bb] = bv.x; Bs[kq * 4 + 1][bb] = bv.y;
      Bs[kq * 4 + 2][bb] = bv.z; Bs[kq * 4 + 3][bb] = bv.w;
    }
    __syncthreads();
    #pragma unroll
    for (int kk = 0; kk < 16; ++kk) {
      float4 a4 = *(const float4*)&As[kk][ts * 4];
      float4 b0 = *(const float4*)&Bs[kk][tb * 16 + 0];
      float4 b1 = *(const float4*)&Bs[kk][tb * 16 + 4];
      float4 b2 = *(const float4*)&Bs[kk][tb * 16 + 8];
      float4 b3 = *(const float4*)&Bs[kk][tb * 16 + 12];
      float aa[4] = {a4.x, a4.y, a4.z, a4.w};
      float bbv[16] = {b0.x, b0.y, b0.z, b0.w, b1.x, b1.y, b1.z, b1.w,
                       b2.x, b2.y, b2.z, b2.w, b3.x, b3.y, b3.z, b3.w};
      #pragma unroll
      for (int i = 0; i < 4; ++i)
        #pragma unroll
        for (int j = 0; j < 16; ++j)
          acc[i][j] = fmaf(aa[i], bbv[j], acc[i][j]);
    }
    __syncthreads();
  }

  // per-thread argmax over its 4 s per b column
  #pragma unroll
  for (int j = 0; j < 16; ++j) {
    float bv = -INFINITY; int bi = 0;
    #pragma unroll
    for (int i = 0; i < 4; ++i) {
      int s = s0 + ts * 4 + i;
      if (s < S_N && acc[i][j] > bv) { bv = acc[i][j]; bi = s; }
    }
    cv[ts][tb * 16 + j] = bv;
    ci[ts][tb * 16 + j] = bi;
  }
  __syncthreads();
  // thread t reduces column b = t across the 16 ts rows, then one atomic
  {
    int bb = t; float bv = -INFINITY; int bi = 0x7FFFFFFF;
    #pragma unroll
    for (int r = 0; r < 16; ++r) {
      float v = cv[r][bb]; int idx = ci[r][bb];
      if (v > bv || (v == bv && idx < bi)) { bv = v; bi = idx; }
    }
    unsigned int u = __float_as_uint(bv);
    u = (u & 0x80000000u) ? ~u : (u | 0x80000000u);  // order-preserving map
    unsigned long long key =
        ((unsigned long long)u << 32) |
        (unsigned long long)(0xFFFFFFFFu - (unsigned)bi);  // ties -> smaller idx
    atomicMax(&keys[bb], key);
  }
}

// -------- K2: nn = normalize(support[nn_idx]); batch_den --------
__global__ __launch_bounds__(256) void k_nn(const float* __restrict__ support,
    const unsigned long long* __restrict__ keys, const float* __restrict__ aug,
    float* __restrict__ nn, float* __restrict__ bden) {
  __shared__ float buf[4];
  int b = blockIdx.x, t = threadIdx.x;
  int idx = (int)(0xFFFFFFFFu - (unsigned)(keys[b] & 0xFFFFFFFFull));
  const float2 rv = *(const float2*)&support[(long long)idx * F_N + t * 2];
  float ss = blockReduceSum256(rv.x * rv.x + rv.y * rv.y, buf);
  float inv = 1.0f / fmaxf(sqrtf(ss), EPSF);
  float nx = rv.x * inv, ny = rv.y * inv;
  nn[b * F_N + t * 2] = nx;
  nn[b * F_N + t * 2 + 1] = ny;
  const float2 a0 = *(const float2*)&aug[(0 * B_N + b) * F_N + t * 2];
  const float2 a1 = *(const float2*)&aug[(1 * B_N + b) * F_N + t * 2];
  float d0 = blockReduceSum256(a0.x * nx + a0.y * ny, buf);
  float d1 = blockReduceSum256(a1.x * nx + a1.y * ny, buf);
  if (t == 0) bden[b] = expf(d0 * 10.0f) + expf(d1 * 10.0f);
}

// -------- K3: per-b queue scan + queue_den + loss term --------
__global__ __launch_bounds__(256) void k_queue(const float* __restrict__ support,
    const float* __restrict__ gps, const float* __restrict__ sgps,
    const float* __restrict__ nn, const float* __restrict__ bden,
    double* __restrict__ terms) {
  __shared__ float nns[F_N];
  __shared__ int qidx[Q_N];
  __shared__ int wtot[4];
  __shared__ double wacc[4];
  int b = blockIdx.x, t = threadIdx.x;
  int lane = t & 63, w = t >> 6;

  *(float2*)&nns[t * 2] = *(const float2*)&nn[b * F_N + t * 2];

  const float DEG2RAD = 0.017453292519943295f;
  float la = gps[b * 2] * DEG2RAD;
  float lo = gps[b * 2 + 1] * DEG2RAD;
  float ca = cosf(la);
  double xd = 25.0 / (2.0 * 6371.0088);
  float hcut = (float)(sin(xd) * sin(xd));  // dist>25km  <=>  h > hcut

  int cnt = 0;
  for (int base = 0; base < S_N; base += 256) {
    int s = base + t;
    bool far = false;
    if (s < S_N) {
      float lb = sgps[s * 2] * DEG2RAD;
      float ob = sgps[s * 2 + 1] * DEG2RAD;
      float sl = sinf((lb - la) * 0.5f);
      float so = sinf((ob - lo) * 0.5f);
      float h = sl * sl + ca * cosf(lb) * so * so;
      far = h > hcut;
    }
    unsigned long long m = __ballot(far);
    if (lane == 0) wtot[w] = (int)__popcll(m);
    __syncthreads();
    int offs = cnt;
    for (int wi = 0; wi < w; ++wi) offs += wtot[wi];
    if (far) {
      int pos = offs + (int)__popcll(m & ((1ull << lane) - 1ull));
      if (pos < Q_N) qidx[pos] = s;
    }
    cnt += wtot[0] + wtot[1] + wtot[2] + wtot[3];
    __syncthreads();
    if (cnt >= Q_N) break;
  }
  int nvalid = cnt < Q_N ? cnt : Q_N;
  __syncthreads();

  double acc = 0.0;
  for (int q = w; q < nvalid; q += 4) {
    const float4* rp =
        (const float4*)&support[(long long)qidx[q] * F_N + lane * 8];
    float4 r0 = rp[0], r1 = rp[1];
    const float4 n0 = *(const float4*)&nns[lane * 8];
    const float4 n1 = *(const float4*)&nns[lane * 8 + 4];
    float dot = r0.x * n0.x + r0.y * n0.y + r0.z * n0.z + r0.w * n0.w +
                r1.x * n1.x + r1.y * n1.y + r1.z * n1.z + r1.w * n1.w;
    float ssq = r0.x * r0.x + r0.y * r0.y + r0.z * r0.z + r0.w * r0.w +
                r1.x * r1.x + r1.y * r1.y + r1.z * r1.z + r1.w * r1.w;
    #pragma unroll
    for (int o = 32; o > 0; o >>= 1) {
      dot += __shfl_xor(dot, o);
      ssq += __shfl_xor(ssq, o);
    }
    float val = dot / fmaxf(sqrtf(ssq), EPSF);
    acc += (double)expf(val * 10.0f);
  }
  if (lane == 0) wacc[w] = acc;
  __syncthreads();
  if (t == 0) {
    double qd = wacc[0] + wacc[1] + wacc[2] + wacc[3] + (double)(Q_N - nvalid);
    double bd = (double)bden[b];
    terms[b] = -bd / (bd + qd);
  }
}

// -------- K4: final mean --------
__global__ __launch_bounds__(256) void k_final(const double* __restrict__ terms,
                                               float* __restrict__ out) {
  __shared__ double buf[4];
  int t = threadIdx.x;
  double v = terms[t];
  #pragma unroll
  for (int o = 32; o > 0; o >>= 1) v += __shfl_down(v, o);
  if ((t & 63) == 0) buf[t >> 6] = v;
  __syncthreads();
  if (t == 0) out[0] = (float)((buf[0] + buf[1] + buf[2] + buf[3]) / 256.0);
}

extern "C" void kernel_launch(void* const* d_in, const int* in_sizes, int n_in,
                              void* d_out, int out_size, void* d_ws, size_t ws_size,
                              hipStream_t stream) {
  const float* V = (const float*)d_in[0];
  const float* L = (const float*)d_in[1];
  const float* gps = (const float*)d_in[2];
  const float* support = (const float*)d_in[3];
  const float* sgps = (const float*)d_in[4];
  float* out = (float*)d_out;

  char* ws = (char*)d_ws;
  unsigned long long* keys = (unsigned long long*)ws;   // 2 KB
  double* terms = (double*)(ws + 2048);                 // 2 KB
  float* bden = (float*)(ws + 4096);                    // 1 KB
  float* org = (float*)(ws + 8192);                     // 512 KB
  float* aug = org + B_N * F_N;                         // 1 MB
  float* nn = aug + 2 * B_N * F_N;                      // 512 KB

  hipMemsetAsync(keys, 0, 256 * sizeof(unsigned long long), stream);
  k_prep<<<256, 256, 0, stream>>>(V, L, org, aug);
  k_sims<<<NCHUNK, 256, 0, stream>>>(support, org, keys);
  k_nn<<<256, 256, 0, stream>>>(support, keys, aug, nn, bden);
  k_queue<<<256, 256, 0, stream>>>(support, gps, sgps, nn, bden, terms);
  k_final<<<1, 256, 0, stream>>>(terms, out);
}

// Round 2
// 325.444 us; speedup vs baseline: 1.6738x; 1.6738x over previous
//
#include <hip/hip_runtime.h>
#include <math.h>

#define B_N 256
#define F_N 512
#define S_N 100000
#define Q_N 1024
#define EPSF 1e-12f
#define BM 64
#define NBLK ((S_N + BM - 1) / BM)   // 1563

typedef __attribute__((ext_vector_type(8))) short short8v;  // 8 bf16
typedef __attribute__((ext_vector_type(4))) float f32x4;

__device__ __forceinline__ unsigned short f2bf(float x) {  // RNE f32->bf16
  unsigned u = __float_as_uint(x);
  u = u + 0x7FFFu + ((u >> 16) & 1u);
  return (unsigned short)(u >> 16);
}
__device__ __forceinline__ float bf2f(unsigned short h) {
  return __uint_as_float(((unsigned)h) << 16);
}

__device__ __forceinline__ float warpReduceSum(float v) {
  #pragma unroll
  for (int o = 32; o > 0; o >>= 1) v += __shfl_down(v, o);
  return v;
}

__device__ __forceinline__ float blockReduceSum256(float v, float* buf) {
  v = warpReduceSum(v);
  int lane = threadIdx.x & 63, w = threadIdx.x >> 6;
  __syncthreads();
  if (lane == 0) buf[w] = v;
  __syncthreads();
  return buf[0] + buf[1] + buf[2] + buf[3];
}

// -------- K0: L_norm, org (hi/lo bf16 pre-swizzled staged layout), aug --------
// org_staged[kt][b][slot^ (b&7)][8]  (slots 0-3 = hi k-subslots, 4-7 = lo)
__global__ __launch_bounds__(256) void k_prep(const float* __restrict__ V,
    const float* __restrict__ L, unsigned short* __restrict__ orgst,
    float* __restrict__ aug) {
  __shared__ float buf[4];
  int b = blockIdx.x, t = threadIdx.x;
  const float2 lv = *(const float2*)&L[b * F_N + t * 2];
  float ss = blockReduceSum256(lv.x * lv.x + lv.y * lv.y, buf);
  float invL = 1.0f / fmaxf(sqrtf(ss), EPSF);
  float lnx = lv.x * invL, lny = lv.y * invL;
  #pragma unroll
  for (int a = 0; a < 3; ++a) {
    const float2 vv = *(const float2*)&V[(a * B_N + b) * F_N + t * 2];
    float yx = vv.x * lnx, yy = vv.y * lny;
    float s2 = blockReduceSum256(yx * yx + yy * yy, buf);
    float inv = 1.0f / fmaxf(sqrtf(s2), EPSF);
    if (a == 0) {
      float ox = yx * inv, oy = yy * inv;
      int f = t * 2;
      int kt = f >> 5, kk = f & 31, sub = kk >> 3, pos = kk & 7;
      unsigned short hx = f2bf(ox), hy = f2bf(oy);
      unsigned short lx = f2bf(ox - bf2f(hx)), ly = f2bf(oy - bf2f(hy));
      int base = kt * 16384 + b * 64;
      ushort2 hv; hv.x = hx; hv.y = hy;
      ushort2 lw; lw.x = lx; lw.y = ly;
      *(ushort2*)&orgst[base + ((sub ^ (b & 7)) << 3) + pos] = hv;
      *(ushort2*)&orgst[base + (((sub | 4) ^ (b & 7)) << 3) + pos] = lw;
    } else {
      float* dst = &aug[((a - 1) * B_N + b) * F_N + t * 2];
      dst[0] = yx * inv;
      dst[1] = yy * inv;
    }
  }
}

// -------- K1: sims GEMM via bf16 hi/lo-split MFMA + per-block argmax --------
// block: 64 s-rows x 256 b. 4 waves (wm 2 x wn 2), wave = 32s x 128b.
__global__ __launch_bounds__(256, 3) void k_sims(const float* __restrict__ support,
    const unsigned short* __restrict__ orgst, unsigned long long* __restrict__ keys) {
  __shared__ __align__(16) unsigned char smem[40960];  // A 8KB | B 32KB

  int t = threadIdx.x;
  int lane = t & 63, wid = t >> 6;
  int wm = wid >> 1, wn = wid & 1;
  int r15 = lane & 15, ks = lane >> 4;
  int s0 = blockIdx.x * BM;

  f32x4 acc[2][8];
  #pragma unroll
  for (int m = 0; m < 2; ++m)
    #pragma unroll
    for (int n = 0; n < 8; ++n) acc[m][n] = (f32x4){0.f, 0.f, 0.f, 0.f};

  int arow = t >> 2, akq = t & 3;
  bool avalid = (s0 + arow) < S_N;
  const float* asrc = support + (size_t)(s0 + arow) * F_N + akq * 8;
  unsigned char* Arow = smem + arow * 128;
  unsigned hoff = ((unsigned)(akq ^ (arow & 7))) << 4;
  unsigned loff = ((unsigned)((akq | 4) ^ (arow & 7))) << 4;

  for (int kt = 0; kt < 16; ++kt) {
    // ---- stage A: 64x32 f32 -> hi/lo bf16, swizzled ----
    float4 a0 = make_float4(0.f, 0.f, 0.f, 0.f), a1 = a0;
    if (avalid) {
      a0 = *(const float4*)(asrc + kt * 32);
      a1 = *(const float4*)(asrc + kt * 32 + 4);
    }
    float xs[8] = {a0.x, a0.y, a0.z, a0.w, a1.x, a1.y, a1.z, a1.w};
    unsigned hw[4], lw[4];
    #pragma unroll
    for (int i = 0; i < 4; ++i) {
      unsigned short h0 = f2bf(xs[2 * i]), h1 = f2bf(xs[2 * i + 1]);
      unsigned short l0 = f2bf(xs[2 * i] - bf2f(h0));
      unsigned short l1 = f2bf(xs[2 * i + 1] - bf2f(h1));
      hw[i] = (unsigned)h0 | ((unsigned)h1 << 16);
      lw[i] = (unsigned)l0 | ((unsigned)l1 << 16);
    }
    *(uint4*)(Arow + hoff) = make_uint4(hw[0], hw[1], hw[2], hw[3]);
    *(uint4*)(Arow + loff) = make_uint4(lw[0], lw[1], lw[2], lw[3]);

    // ---- stage B: verbatim 32KB copy of pre-swizzled org_staged[kt] ----
    const uint4* gBk = (const uint4*)((const unsigned char*)orgst + (size_t)kt * 32768);
    #pragma unroll
    for (int i = 0; i < 8; ++i) {
      uint4 v = gBk[i * 256 + t];
      *(uint4*)(smem + 8192 + (i * 256 + t) * 16) = v;
    }
    __syncthreads();

    // ---- compute: 4 cross-products (hi+lo)x(hi+lo) ----
    short8v ah[2], al[2];
    #pragma unroll
    for (int m = 0; m < 2; ++m) {
      int row = wm * 32 + m * 16 + r15;
      unsigned char* p = smem + row * 128;
      int sw = row & 7;
      ah[m] = *(const short8v*)(p + ((ks ^ sw) << 4));
      al[m] = *(const short8v*)(p + (((ks | 4) ^ sw) << 4));
    }
    #pragma unroll
    for (int n = 0; n < 8; ++n) {
      int col = wn * 128 + n * 16 + r15;
      unsigned char* p = smem + 8192 + col * 128;
      int sw = col & 7;
      short8v bh = *(const short8v*)(p + ((ks ^ sw) << 4));
      short8v bl = *(const short8v*)(p + (((ks | 4) ^ sw) << 4));
      #pragma unroll
      for (int m = 0; m < 2; ++m) {
        acc[m][n] = __builtin_amdgcn_mfma_f32_16x16x32_bf16(ah[m], bh, acc[m][n], 0, 0, 0);
        acc[m][n] = __builtin_amdgcn_mfma_f32_16x16x32_bf16(al[m], bh, acc[m][n], 0, 0, 0);
        acc[m][n] = __builtin_amdgcn_mfma_f32_16x16x32_bf16(ah[m], bl, acc[m][n], 0, 0, 0);
        acc[m][n] = __builtin_amdgcn_mfma_f32_16x16x32_bf16(al[m], bl, acc[m][n], 0, 0, 0);
      }
    }
    __syncthreads();
  }

  // ---- per-block argmax: C/D layout col=lane&15, row=(lane>>4)*4+reg ----
  unsigned long long* wk = (unsigned long long*)smem;  // [wm 2][256] overlay
  #pragma unroll
  for (int n = 0; n < 8; ++n) {
    float bv = -INFINITY;
    int bi = 0x7FFFFFFF;
    #pragma unroll
    for (int m = 0; m < 2; ++m)
      #pragma unroll
      for (int r = 0; r < 4; ++r) {
        int s = s0 + wm * 32 + m * 16 + ks * 4 + r;
        float v = acc[m][n][r];
        if (s < S_N && (v > bv || (v == bv && s < bi))) { bv = v; bi = s; }
      }
    #pragma unroll
    for (int mask = 16; mask <= 32; mask <<= 1) {
      float ov = __shfl_xor(bv, mask);
      int oi = __shfl_xor(bi, mask);
      if (ov > bv || (ov == bv && oi < bi)) { bv = ov; bi = oi; }
    }
    if (lane < 16) {
      unsigned u = __float_as_uint(bv);
      u = (u & 0x80000000u) ? ~u : (u | 0x80000000u);
      wk[wm * 256 + wn * 128 + n * 16 + lane] =
          ((unsigned long long)u << 32) |
          (unsigned long long)(0xFFFFFFFFu - (unsigned)bi);
    }
  }
  __syncthreads();
  if (t < 256) {
    unsigned long long k0 = wk[t], k1 = wk[256 + t];
    atomicMax(&keys[t], k0 > k1 ? k0 : k1);
  }
}

// -------- K2: nn = normalize(support[nn_idx]); batch_den --------
__global__ __launch_bounds__(256) void k_nn(const float* __restrict__ support,
    const unsigned long long* __restrict__ keys, const float* __restrict__ aug,
    float* __restrict__ nn, float* __restrict__ bden) {
  __shared__ float buf[4];
  int b = blockIdx.x, t = threadIdx.x;
  int idx = (int)(0xFFFFFFFFu - (unsigned)(keys[b] & 0xFFFFFFFFull));
  const float2 rv = *(const float2*)&support[(size_t)idx * F_N + t * 2];
  float ss = blockReduceSum256(rv.x * rv.x + rv.y * rv.y, buf);
  float inv = 1.0f / fmaxf(sqrtf(ss), EPSF);
  float nx = rv.x * inv, ny = rv.y * inv;
  nn[b * F_N + t * 2] = nx;
  nn[b * F_N + t * 2 + 1] = ny;
  const float2 a0 = *(const float2*)&aug[(0 * B_N + b) * F_N + t * 2];
  const float2 a1 = *(const float2*)&aug[(1 * B_N + b) * F_N + t * 2];
  float d0 = blockReduceSum256(a0.x * nx + a0.y * ny, buf);
  float d1 = blockReduceSum256(a1.x * nx + a1.y * ny, buf);
  if (t == 0) bden[b] = expf(d0 * 10.0f) + expf(d1 * 10.0f);
}

// -------- K3: per-b queue scan + queue_den + loss term --------
__global__ __launch_bounds__(256) void k_queue(const float* __restrict__ support,
    const float* __restrict__ gps, const float* __restrict__ sgps,
    const float* __restrict__ nn, const float* __restrict__ bden,
    double* __restrict__ terms) {
  __shared__ float nns[F_N];
  __shared__ int qidx[Q_N];
  __shared__ int wtot[4];
  __shared__ double wacc[4];
  int b = blockIdx.x, t = threadIdx.x;
  int lane = t & 63, w = t >> 6;

  *(float2*)&nns[t * 2] = *(const float2*)&nn[b * F_N + t * 2];

  const float DEG2RAD = 0.017453292519943295f;
  float la = gps[b * 2] * DEG2RAD;
  float lo = gps[b * 2 + 1] * DEG2RAD;
  float ca = cosf(la);
  double xd = 25.0 / (2.0 * 6371.0088);
  float hcut = (float)(sin(xd) * sin(xd));  // dist>25km  <=>  h > hcut

  int cnt = 0;
  for (int base = 0; base < S_N; base += 256) {
    int s = base + t;
    bool far = false;
    if (s < S_N) {
      float lb = sgps[s * 2] * DEG2RAD;
      float ob = sgps[s * 2 + 1] * DEG2RAD;
      float sl = sinf((lb - la) * 0.5f);
      float so = sinf((ob - lo) * 0.5f);
      float h = sl * sl + ca * cosf(lb) * so * so;
      far = h > hcut;
    }
    unsigned long long m = __ballot(far);
    if (lane == 0) wtot[w] = (int)__popcll(m);
    __syncthreads();
    int offs = cnt;
    for (int wi = 0; wi < w; ++wi) offs += wtot[wi];
    if (far) {
      int pos = offs + (int)__popcll(m & ((1ull << lane) - 1ull));
      if (pos < Q_N) qidx[pos] = s;
    }
    cnt += wtot[0] + wtot[1] + wtot[2] + wtot[3];
    __syncthreads();
    if (cnt >= Q_N) break;
  }
  int nvalid = cnt < Q_N ? cnt : Q_N;
  __syncthreads();

  double acc = 0.0;
  for (int q = w; q < nvalid; q += 4) {
    const float4* rp = (const float4*)&support[(size_t)qidx[q] * F_N + lane * 8];
    float4 r0 = rp[0], r1 = rp[1];
    const float4 n0 = *(const float4*)&nns[lane * 8];
    const float4 n1 = *(const float4*)&nns[lane * 8 + 4];
    float dot = r0.x * n0.x + r0.y * n0.y + r0.z * n0.z + r0.w * n0.w +
                r1.x * n1.x + r1.y * n1.y + r1.z * n1.z + r1.w * n1.w;
    float ssq = r0.x * r0.x + r0.y * r0.y + r0.z * r0.z + r0.w * r0.w +
                r1.x * r1.x + r1.y * r1.y + r1.z * r1.z + r1.w * r1.w;
    #pragma unroll
    for (int o = 32; o > 0; o >>= 1) {
      dot += __shfl_xor(dot, o);
      ssq += __shfl_xor(ssq, o);
    }
    float val = dot / fmaxf(sqrtf(ssq), EPSF);
    acc += (double)expf(val * 10.0f);
  }
  if (lane == 0) wacc[w] = acc;
  __syncthreads();
  if (t == 0) {
    double qd = wacc[0] + wacc[1] + wacc[2] + wacc[3] + (double)(Q_N - nvalid);
    double bd = (double)bden[b];
    terms[b] = -bd / (bd + qd);
  }
}

// -------- K4: final mean --------
__global__ __launch_bounds__(256) void k_final(const double* __restrict__ terms,
                                               float* __restrict__ out) {
  __shared__ double buf[4];
  int t = threadIdx.x;
  double v = terms[t];
  #pragma unroll
  for (int o = 32; o > 0; o >>= 1) v += __shfl_down(v, o);
  if ((t & 63) == 0) buf[t >> 6] = v;
  __syncthreads();
  if (t == 0) out[0] = (float)((buf[0] + buf[1] + buf[2] + buf[3]) / 256.0);
}

extern "C" void kernel_launch(void* const* d_in, const int* in_sizes, int n_in,
                              void* d_out, int out_size, void* d_ws, size_t ws_size,
                              hipStream_t stream) {
  const float* V = (const float*)d_in[0];
  const float* L = (const float*)d_in[1];
  const float* gps = (const float*)d_in[2];
  const float* support = (const float*)d_in[3];
  const float* sgps = (const float*)d_in[4];
  float* out = (float*)d_out;

  char* ws = (char*)d_ws;
  unsigned long long* keys = (unsigned long long*)ws;      // 2 KB
  double* terms = (double*)(ws + 2048);                    // 2 KB
  float* bden = (float*)(ws + 4096);                       // 1 KB
  unsigned short* orgst = (unsigned short*)(ws + 8192);    // 512 KB
  float* aug = (float*)(ws + 8192 + 524288);               // 1 MB
  float* nn = (float*)(ws + 8192 + 524288 + 1048576);      // 512 KB

  hipMemsetAsync(keys, 0, 256 * sizeof(unsigned long long), stream);
  k_prep<<<256, 256, 0, stream>>>(V, L, orgst, aug);
  k_sims<<<NBLK, 256, 0, stream>>>(support, orgst, keys);
  k_nn<<<256, 256, 0, stream>>>(support, keys, aug, nn, bden);
  k_queue<<<256, 256, 0, stream>>>(support, gps, sgps, nn, bden, terms);
  k_final<<<1, 256, 0, stream>>>(terms, out);
}

// Round 3
// 167.296 us; speedup vs baseline: 3.2560x; 1.9453x over previous
//
#include <hip/hip_runtime.h>
#include <hip/hip_bf16.h>
#include <math.h>

#define B_N 256
#define F_N 512
#define S_N 100000
#define Q_N 1024
#define EPSF 1e-12f
#define BM 128
#define NBLK ((S_N + BM - 1) / BM)   // 782

typedef __attribute__((ext_vector_type(8))) short short8v;  // 8 bf16
typedef __attribute__((ext_vector_type(4))) float f32x4;

__device__ __forceinline__ unsigned short f2bf(float x) {  // RNE f32->bf16
  unsigned u = __float_as_uint(x);
  u = u + 0x7FFFu + ((u >> 16) & 1u);
  return (unsigned short)(u >> 16);
}
__device__ __forceinline__ float bf2f(unsigned short h) {
  return __uint_as_float(((unsigned)h) << 16);
}

__device__ __forceinline__ float warpReduceSum(float v) {
  #pragma unroll
  for (int o = 32; o > 0; o >>= 1) v += __shfl_down(v, o);
  return v;
}

__device__ __forceinline__ float blockReduceSum256(float v, float* buf) {
  v = warpReduceSum(v);
  int lane = threadIdx.x & 63, w = threadIdx.x >> 6;
  __syncthreads();
  if (lane == 0) buf[w] = v;
  __syncthreads();
  return buf[0] + buf[1] + buf[2] + buf[3];
}

__device__ __forceinline__ void async_copy16(void* lds, const void* g) {
  __builtin_amdgcn_global_load_lds(
      (const __attribute__((address_space(1))) unsigned int*)g,
      (__attribute__((address_space(3))) unsigned int*)lds, 16, 0, 0);
}

// convert 8 f32 -> hi/lo bf16 fragments (pairs via v_cvt_pk_bf16_f32)
__device__ __forceinline__ void cvt8(const float4 a, const float4 b,
                                     short8v& hi, short8v& lo) {
  union { unsigned u[4]; short8v v; } H, L;
  float xs[8] = {a.x, a.y, a.z, a.w, b.x, b.y, b.z, b.w};
  #pragma unroll
  for (int i = 0; i < 4; ++i) {
    float p = xs[2 * i], q = xs[2 * i + 1];
    union { __hip_bfloat162 b2; unsigned u; } c;
    c.b2 = __float22bfloat162_rn(make_float2(p, q));
    H.u[i] = c.u;
    float rp = p - __uint_as_float(c.u << 16);
    float rq = q - __uint_as_float(c.u & 0xFFFF0000u);
    union { __hip_bfloat162 b2; unsigned u; } d;
    d.b2 = __float22bfloat162_rn(make_float2(rp, rq));
    L.u[i] = d.u;
  }
  hi = H.v; lo = L.v;
}

// -------- K0: L_norm, org (hi/lo bf16 pre-swizzled staged layout), aug --------
// orgst[kt][b][slot^(b&7)][8]  (slots 0-3 = hi k-subslots, 4-7 = lo)
__global__ __launch_bounds__(256) void k_prep(const float* __restrict__ V,
    const float* __restrict__ L, unsigned short* __restrict__ orgst,
    float* __restrict__ aug) {
  __shared__ float buf[4];
  int b = blockIdx.x, t = threadIdx.x;
  const float2 lv = *(const float2*)&L[b * F_N + t * 2];
  float ss = blockReduceSum256(lv.x * lv.x + lv.y * lv.y, buf);
  float invL = 1.0f / fmaxf(sqrtf(ss), EPSF);
  float lnx = lv.x * invL, lny = lv.y * invL;
  #pragma unroll
  for (int a = 0; a < 3; ++a) {
    const float2 vv = *(const float2*)&V[(a * B_N + b) * F_N + t * 2];
    float yx = vv.x * lnx, yy = vv.y * lny;
    float s2 = blockReduceSum256(yx * yx + yy * yy, buf);
    float inv = 1.0f / fmaxf(sqrtf(s2), EPSF);
    if (a == 0) {
      float ox = yx * inv, oy = yy * inv;
      int f = t * 2;
      int kt = f >> 5, kk = f & 31, sub = kk >> 3, pos = kk & 7;
      unsigned short hx = f2bf(ox), hy = f2bf(oy);
      unsigned short lx = f2bf(ox - bf2f(hx)), ly = f2bf(oy - bf2f(hy));
      int base = kt * 16384 + b * 64;
      ushort2 hv; hv.x = hx; hv.y = hy;
      ushort2 lw; lw.x = lx; lw.y = ly;
      *(ushort2*)&orgst[base + ((sub ^ (b & 7)) << 3) + pos] = hv;
      *(ushort2*)&orgst[base + (((sub | 4) ^ (b & 7)) << 3) + pos] = lw;
    } else {
      float* dst = &aug[((a - 1) * B_N + b) * F_N + t * 2];
      dst[0] = yx * inv;
      dst[1] = yy * inv;
    }
  }
}

// -------- K1: sims GEMM. BM=128, 4 waves, wave tile 32s x 256b. --------
// A: direct HBM->reg (rows unique per wave). B: LDS dbuf via global_load_lds,
// 1 barrier per kt (stage kt+1 before compute kt). 3-pass hi/lo MFMA.
__global__ __launch_bounds__(256, 2) void k_sims(const float* __restrict__ support,
    const unsigned short* __restrict__ orgst, unsigned long long* __restrict__ keys) {
  __shared__ __align__(16) unsigned char smem[65536];  // B dbuf 2x32KB

  int t = threadIdx.x;
  int lane = t & 63, w = t >> 6;
  int r15 = lane & 15, ks = lane >> 4;
  int s0 = blockIdx.x * BM;

  f32x4 acc0[16], acc1[16];
  #pragma unroll
  for (int n = 0; n < 16; ++n) {
    acc0[n] = (f32x4){0.f, 0.f, 0.f, 0.f};
    acc1[n] = (f32x4){0.f, 0.f, 0.f, 0.f};
  }

  int row0 = s0 + w * 32 + r15;       // m=0
  int row1 = row0 + 16;               // m=1
  if (row0 > S_N - 1) row0 = S_N - 1;
  if (row1 > S_N - 1) row1 = S_N - 1;
  const float* ap0 = support + (size_t)row0 * F_N + ks * 8;
  const float* ap1 = support + (size_t)row1 * F_N + ks * 8;

  // prologue: stage B(kt=0) into buf0, load A(kt=0)
  {
    const unsigned char* src = (const unsigned char*)orgst + t * 16;
    unsigned char* dst = smem + t * 16;
    #pragma unroll
    for (int p = 0; p < 8; ++p) async_copy16(dst + p * 4096, src + p * 4096);
  }
  float4 a0a = *(const float4*)(ap0);
  float4 a0b = *(const float4*)(ap0 + 4);
  float4 a1a = *(const float4*)(ap1);
  float4 a1b = *(const float4*)(ap1 + 4);
  __syncthreads();

  const int hioff = (ks ^ (r15 & 7)) << 4;
  const int looff = ((ks | 4) ^ (r15 & 7)) << 4;

  #pragma unroll 1
  for (int kt = 0; kt < 16; ++kt) {
    const int cur = kt & 1;
    unsigned char* bbuf = smem + cur * 32768;
    // stage next B tile into the other buffer (in flight across compute)
    if (kt < 15) {
      const unsigned char* src =
          (const unsigned char*)orgst + (kt + 1) * 32768 + t * 16;
      unsigned char* dst = smem + (cur ^ 1) * 32768 + t * 16;
      #pragma unroll
      for (int p = 0; p < 8; ++p) async_copy16(dst + p * 4096, src + p * 4096);
    }
    // convert current A regs to hi/lo fragments
    short8v ah0, al0, ah1, al1;
    cvt8(a0a, a0b, ah0, al0);
    cvt8(a1a, a1b, ah1, al1);
    // prefetch next A
    if (kt < 15) {
      a0a = *(const float4*)(ap0 + (kt + 1) * 32);
      a0b = *(const float4*)(ap0 + (kt + 1) * 32 + 4);
      a1a = *(const float4*)(ap1 + (kt + 1) * 32);
      a1b = *(const float4*)(ap1 + (kt + 1) * 32 + 4);
    }
    // compute: 16 n-tiles x (2m x 3 passes)
    const unsigned char* bp = bbuf + r15 * 128 + hioff;
    const unsigned char* bq = bbuf + r15 * 128 + looff;
    #pragma unroll
    for (int n = 0; n < 16; ++n) {
      short8v bh = *(const short8v*)(bp + n * 2048);
      short8v bl = *(const short8v*)(bq + n * 2048);
      acc0[n] = __builtin_amdgcn_mfma_f32_16x16x32_bf16(ah0, bh, acc0[n], 0, 0, 0);
      acc1[n] = __builtin_amdgcn_mfma_f32_16x16x32_bf16(ah1, bh, acc1[n], 0, 0, 0);
      acc0[n] = __builtin_amdgcn_mfma_f32_16x16x32_bf16(al0, bh, acc0[n], 0, 0, 0);
      acc1[n] = __builtin_amdgcn_mfma_f32_16x16x32_bf16(al1, bh, acc1[n], 0, 0, 0);
      acc0[n] = __builtin_amdgcn_mfma_f32_16x16x32_bf16(ah0, bl, acc0[n], 0, 0, 0);
      acc1[n] = __builtin_amdgcn_mfma_f32_16x16x32_bf16(ah1, bl, acc1[n], 0, 0, 0);
    }
    __syncthreads();  // drains gload_lds vmcnt; all waves done reading bbuf
  }

  // ---- per-block argmax: C layout col=lane&15, row=(lane>>4)*4+reg ----
  unsigned long long* wk = (unsigned long long*)smem;  // 4x256 u64 (buf0 area)
  #pragma unroll
  for (int n = 0; n < 16; ++n) {
    float bv = -INFINITY;
    int bi = 0x7FFFFFFF;
    #pragma unroll
    for (int r = 0; r < 4; ++r) {
      int sA = s0 + w * 32 + ks * 4 + r;
      float vA = acc0[n][r];
      if (sA < S_N && (vA > bv || (vA == bv && sA < bi))) { bv = vA; bi = sA; }
      int sB = sA + 16;
      float vB = acc1[n][r];
      if (sB < S_N && (vB > bv || (vB == bv && sB < bi))) { bv = vB; bi = sB; }
    }
    #pragma unroll
    for (int mask = 16; mask <= 32; mask <<= 1) {
      float ov = __shfl_xor(bv, mask);
      int oi = __shfl_xor(bi, mask);
      if (ov > bv || (ov == bv && oi < bi)) { bv = ov; bi = oi; }
    }
    if (lane < 16) {
      unsigned u = __float_as_uint(bv);
      u = (u & 0x80000000u) ? ~u : (u | 0x80000000u);
      wk[w * 256 + n * 16 + lane] =
          ((unsigned long long)u << 32) |
          (unsigned long long)(0xFFFFFFFFu - (unsigned)bi);
    }
  }
  __syncthreads();
  {
    unsigned long long k0 = wk[t], k1 = wk[256 + t];
    unsigned long long k2 = wk[512 + t], k3 = wk[768 + t];
    unsigned long long m01 = k0 > k1 ? k0 : k1;
    unsigned long long m23 = k2 > k3 ? k2 : k3;
    atomicMax(&keys[t], m01 > m23 ? m01 : m23);
  }
}

// -------- K2: nn = normalize(support[nn_idx]); batch_den --------
__global__ __launch_bounds__(256) void k_nn(const float* __restrict__ support,
    const unsigned long long* __restrict__ keys, const float* __restrict__ aug,
    float* __restrict__ nn, float* __restrict__ bden) {
  __shared__ float buf[4];
  int b = blockIdx.x, t = threadIdx.x;
  int idx = (int)(0xFFFFFFFFu - (unsigned)(keys[b] & 0xFFFFFFFFull));
  const float2 rv = *(const float2*)&support[(size_t)idx * F_N + t * 2];
  float ss = blockReduceSum256(rv.x * rv.x + rv.y * rv.y, buf);
  float inv = 1.0f / fmaxf(sqrtf(ss), EPSF);
  float nx = rv.x * inv, ny = rv.y * inv;
  nn[b * F_N + t * 2] = nx;
  nn[b * F_N + t * 2 + 1] = ny;
  const float2 a0 = *(const float2*)&aug[(0 * B_N + b) * F_N + t * 2];
  const float2 a1 = *(const float2*)&aug[(1 * B_N + b) * F_N + t * 2];
  float d0 = blockReduceSum256(a0.x * nx + a0.y * ny, buf);
  float d1 = blockReduceSum256(a1.x * nx + a1.y * ny, buf);
  if (t == 0) bden[b] = expf(d0 * 10.0f) + expf(d1 * 10.0f);
}

// -------- K3: queue dots, 4 blocks per b (chunk c of 256 q each) --------
__global__ __launch_bounds__(256) void k_qdot(const float* __restrict__ support,
    const float* __restrict__ gps, const float* __restrict__ sgps,
    const float* __restrict__ nn, double* __restrict__ qpart) {
  __shared__ float nns[F_N];
  __shared__ int qi[256];
  __shared__ int wtot[4];
  __shared__ double wacc[4];
  int b = blockIdx.x >> 2, c = blockIdx.x & 3;
  int t = threadIdx.x;
  int lane = t & 63, w = t >> 6;

  *(float2*)&nns[t * 2] = *(const float2*)&nn[b * F_N + t * 2];

  const float DEG2RAD = 0.017453292519943295f;
  float la = gps[b * 2] * DEG2RAD;
  float lo = gps[b * 2 + 1] * DEG2RAD;
  float ca = cosf(la);
  double xd = 25.0 / (2.0 * 6371.0088);
  float hcut = (float)(sin(xd) * sin(xd));  // dist>25km  <=>  h > hcut

  int cnt = 0;
  int qlo = c * 256;
  for (int base = 0; base < S_N; base += 256) {
    int s = base + t;
    bool far = false;
    if (s < S_N) {
      float lb = sgps[s * 2] * DEG2RAD;
      float ob = sgps[s * 2 + 1] * DEG2RAD;
      float sl = sinf((lb - la) * 0.5f);
      float so = sinf((ob - lo) * 0.5f);
      float h = sl * sl + ca * cosf(lb) * so * so;
      far = h > hcut;
    }
    unsigned long long m = __ballot(far);
    if (lane == 0) wtot[w] = (int)__popcll(m);
    __syncthreads();
    int offs = cnt;
    for (int wi = 0; wi < w; ++wi) offs += wtot[wi];
    if (far) {
      int pos = offs + (int)__popcll(m & ((1ull << lane) - 1ull));
      int rel = pos - qlo;
      if (rel >= 0 && rel < 256) qi[rel] = s;
    }
    cnt += wtot[0] + wtot[1] + wtot[2] + wtot[3];
    __syncthreads();
    if (cnt >= Q_N) break;
  }
  int nvalid = cnt < Q_N ? cnt : Q_N;
  __syncthreads();

  double acc = 0.0;
  for (int j = 0; j < 64; ++j) {
    int q = qlo + w * 64 + j;
    if (q >= nvalid) break;
    int row = qi[w * 64 + j];
    const float4* rp = (const float4*)&support[(size_t)row * F_N + lane * 8];
    float4 r0 = rp[0], r1 = rp[1];
    const float4 n0 = *(const float4*)&nns[lane * 8];
    const float4 n1 = *(const float4*)&nns[lane * 8 + 4];
    float dot = r0.x * n0.x + r0.y * n0.y + r0.z * n0.z + r0.w * n0.w +
                r1.x * n1.x + r1.y * n1.y + r1.z * n1.z + r1.w * n1.w;
    float ssq = r0.x * r0.x + r0.y * r0.y + r0.z * r0.z + r0.w * r0.w +
                r1.x * r1.x + r1.y * r1.y + r1.z * r1.z + r1.w * r1.w;
    #pragma unroll
    for (int o = 32; o > 0; o >>= 1) {
      dot += __shfl_xor(dot, o);
      ssq += __shfl_xor(ssq, o);
    }
    float val = dot / fmaxf(sqrtf(ssq), EPSF);
    acc += (double)expf(val * 10.0f);
  }
  if (lane == 0) wacc[w] = acc;
  __syncthreads();
  if (t == 0) {
    int got = nvalid - qlo;                 // valid q in this chunk
    if (got < 0) got = 0; if (got > 256) got = 256;
    int inval = 256 - got;                  // zero rows contribute exp(0)=1
    qpart[blockIdx.x] = wacc[0] + wacc[1] + wacc[2] + wacc[3] + (double)inval;
  }
}

// -------- K4: fold qpart + bden -> loss --------
__global__ __launch_bounds__(256) void k_final(const double* __restrict__ qpart,
    const float* __restrict__ bden, float* __restrict__ out) {
  __shared__ double buf[4];
  int t = threadIdx.x;
  double qd = qpart[t * 4] + qpart[t * 4 + 1] + qpart[t * 4 + 2] + qpart[t * 4 + 3];
  double bd = (double)bden[t];
  double v = -bd / (bd + qd);
  #pragma unroll
  for (int o = 32; o > 0; o >>= 1) v += __shfl_down(v, o);
  if ((t & 63) == 0) buf[t >> 6] = v;
  __syncthreads();
  if (t == 0) out[0] = (float)((buf[0] + buf[1] + buf[2] + buf[3]) / 256.0);
}

extern "C" void kernel_launch(void* const* d_in, const int* in_sizes, int n_in,
                              void* d_out, int out_size, void* d_ws, size_t ws_size,
                              hipStream_t stream) {
  const float* V = (const float*)d_in[0];
  const float* L = (const float*)d_in[1];
  const float* gps = (const float*)d_in[2];
  const float* support = (const float*)d_in[3];
  const float* sgps = (const float*)d_in[4];
  float* out = (float*)d_out;

  char* ws = (char*)d_ws;
  unsigned long long* keys = (unsigned long long*)ws;      // 2 KB @0
  float* bden = (float*)(ws + 2048);                       // 1 KB
  double* qpart = (double*)(ws + 4096);                    // 8 KB
  unsigned short* orgst = (unsigned short*)(ws + 12288);   // 512 KB
  float* aug = (float*)(ws + 12288 + 524288);              // 1 MB
  float* nn = (float*)(ws + 12288 + 524288 + 1048576);     // 512 KB

  hipMemsetAsync(keys, 0, 256 * sizeof(unsigned long long), stream);
  k_prep<<<256, 256, 0, stream>>>(V, L, orgst, aug);
  k_sims<<<NBLK, 256, 0, stream>>>(support, orgst, keys);
  k_nn<<<256, 256, 0, stream>>>(support, keys, aug, nn, bden);
  k_qdot<<<1024, 256, 0, stream>>>(support, gps, sgps, nn, qpart);
  k_final<<<1, 256, 0, stream>>>(qpart, bden, out);
}